// Round 1
// baseline (2062.253 us; speedup 1.0000x reference)
//
#include <hip/hip_runtime.h>

#define NB 2048
#define NT 2048
#define NH 16

#define OFF_IMP   1L
#define OFF_TRAIN (1L + (long)NB * NT)
#define OFF_EVALS (OFF_TRAIN + NB)
#define OFF_EMASK (OFF_EVALS + (long)NB * NT)

// ---------------- copies + workspace zeroing ----------------
__global__ void copy_zero_kernel(const float* __restrict__ evals,
                                 const float* __restrict__ emask,
                                 const float* __restrict__ is_train,
                                 float* __restrict__ out,
                                 float* __restrict__ numden) {
    long gid = (long)blockIdx.x * blockDim.x + threadIdx.x;
    if (gid < 2 * NT) numden[gid] = 0.0f;  // zero num[NT] + den[NT] every call
    const long n1 = (long)NB * NT;
    const long total = NB + 2 * n1;
    const long stride = (long)gridDim.x * blockDim.x;
    for (long i = gid; i < total; i += stride) {
        if (i < NB)            out[OFF_TRAIN + i] = is_train[i];
        else if (i < NB + n1)  out[OFF_EVALS + (i - NB)] = evals[i - NB];
        else                   out[OFF_EMASK + (i - NB - n1)] = emask[i - NB - n1];
    }
}

// ---------------- LSTM scan ----------------
__device__ __forceinline__ float sigmf(float x) { return 1.0f / (1.0f + __expf(-x)); }
__device__ __forceinline__ float tanh_fast(float x) { return 1.0f - 2.0f / (1.0f + __expf(2.0f * x)); }

// 16 lanes per batch (lane j = hidden unit j), 4 batches per 64-thread block.
__launch_bounds__(64, 1)
__global__ void lstm_kernel(const float* __restrict__ values,
                            const float* __restrict__ masks,
                            const float* __restrict__ W_ih,
                            const float* __restrict__ W_hh,
                            const float* __restrict__ b_ih,
                            const float* __restrict__ b_hh,
                            const float* __restrict__ W_reg,
                            const float* __restrict__ b_reg,
                            float* __restrict__ imp,   // out + OFF_IMP
                            float* __restrict__ num,
                            float* __restrict__ den) {
    const int lane = threadIdx.x;
    const int g = lane >> 4;       // batch slot within block
    const int j = lane & 15;       // hidden unit
    const long b = (long)blockIdx.x * 4 + g;

    // Per-lane weights: 4 W_hh rows (gate i/f/g/o for unit j) + full W_reg
    float Wi[NH], Wf[NH], Wg[NH], Wo[NH], Wr[NH];
#pragma unroll
    for (int k = 0; k < NH; k += 4) {
        float4 v;
        v = *(const float4*)(W_hh + (0 * NH + j) * NH + k); Wi[k]=v.x; Wi[k+1]=v.y; Wi[k+2]=v.z; Wi[k+3]=v.w;
        v = *(const float4*)(W_hh + (1 * NH + j) * NH + k); Wf[k]=v.x; Wf[k+1]=v.y; Wf[k+2]=v.z; Wf[k+3]=v.w;
        v = *(const float4*)(W_hh + (2 * NH + j) * NH + k); Wg[k]=v.x; Wg[k+1]=v.y; Wg[k+2]=v.z; Wg[k+3]=v.w;
        v = *(const float4*)(W_hh + (3 * NH + j) * NH + k); Wo[k]=v.x; Wo[k+1]=v.y; Wo[k+2]=v.z; Wo[k+3]=v.w;
        v = *(const float4*)(W_reg + k);                    Wr[k]=v.x; Wr[k+1]=v.y; Wr[k+2]=v.z; Wr[k+3]=v.w;
    }
    const float wi0 = W_ih[(0*NH + j)*2 + 0], wi1 = W_ih[(0*NH + j)*2 + 1];
    const float wf0 = W_ih[(1*NH + j)*2 + 0], wf1 = W_ih[(1*NH + j)*2 + 1];
    const float wg0 = W_ih[(2*NH + j)*2 + 0], wg1 = W_ih[(2*NH + j)*2 + 1];
    const float wo0 = W_ih[(3*NH + j)*2 + 0], wo1 = W_ih[(3*NH + j)*2 + 1];
    const float bi = b_ih[0*NH + j] + b_hh[0*NH + j];
    const float bf = b_ih[1*NH + j] + b_hh[1*NH + j];
    const float bg = b_ih[2*NH + j] + b_hh[2*NH + j];
    const float bo = b_ih[3*NH + j] + b_hh[3*NH + j];
    const float brg = b_reg[0];

    float h[NH];
#pragma unroll
    for (int k = 0; k < NH; ++k) h[k] = 0.0f;
    float c = 0.0f;

    __shared__ float hsh[4 * 20];  // stride 20 -> conflict-free across 4 batch groups

    const float* vb = values + b * NT;
    const float* mb = masks + b * NT;
    float* ib = imp + b * NT;

    float4 xv = *(const float4*)(vb);
    float4 mv = *(const float4*)(mb);

    for (int t4 = 0; t4 < NT; t4 += 4) {
        const int tn = (t4 + 4 < NT) ? (t4 + 4) : t4;  // clamped prefetch
        float4 xn = *(const float4*)(vb + tn);
        float4 mn = *(const float4*)(mb + tn);
        float ximp0, ximp1, ximp2, ximp3;
#pragma unroll
        for (int s = 0; s < 4; ++s) {
            const int t = t4 + s;
            const float x = (s == 0) ? xv.x : (s == 1) ? xv.y : (s == 2) ? xv.z : xv.w;
            const float m = (s == 0) ? mv.x : (s == 1) ? mv.y : (s == 2) ? mv.z : mv.w;

            float xh = brg;
#pragma unroll
            for (int k = 0; k < NH; ++k) xh = fmaf(h[k], Wr[k], xh);
            const float xc = m * x + (1.0f - m) * xh;

            if (j == 0) {
                atomicAdd(num + t, fabsf(x - xh) * m);
                atomicAdd(den + t, m);
            }

            float gi = fmaf(wi0, xc, fmaf(wi1, m, bi));
            float gf = fmaf(wf0, xc, fmaf(wf1, m, bf));
            float gg = fmaf(wg0, xc, fmaf(wg1, m, bg));
            float go = fmaf(wo0, xc, fmaf(wo1, m, bo));
#pragma unroll
            for (int k = 0; k < NH; ++k) {
                gi = fmaf(Wi[k], h[k], gi);
                gf = fmaf(Wf[k], h[k], gf);
                gg = fmaf(Wg[k], h[k], gg);
                go = fmaf(Wo[k], h[k], go);
            }
            const float ai = sigmf(gi);
            const float af = sigmf(gf);
            const float ag = tanh_fast(gg);
            const float ao = sigmf(go);
            c = fmaf(af, c, ai * ag);
            const float ht = ao * tanh_fast(c);

            // share h across the 16 lanes of this batch group
            hsh[g * 20 + j] = ht;
            __syncthreads();  // block == 1 wave; compiler/memory fence + lgkm drain
#pragma unroll
            for (int k = 0; k < NH; k += 4) {
                float4 hv = *(const float4*)(&hsh[g * 20 + k]);
                h[k] = hv.x; h[k+1] = hv.y; h[k+2] = hv.z; h[k+3] = hv.w;
            }
            if (s == 0) ximp0 = xc; else if (s == 1) ximp1 = xc; else if (s == 2) ximp2 = xc; else ximp3 = xc;
        }
        // out+1 base breaks 16B alignment -> scalar dword stores by lanes 0..3 (coalesced)
        const float iv = (j == 0) ? ximp0 : (j == 1) ? ximp1 : (j == 2) ? ximp2 : ximp3;
        if (j < 4) ib[t4 + j] = iv;
        xv = xn; mv = mn;
    }
}

// ---------------- loss finalize ----------------
__global__ void loss_kernel(const float* __restrict__ num, const float* __restrict__ den,
                            float* __restrict__ out) {
    const int tid = threadIdx.x;
    float s = 0.0f;
    for (int t = tid; t < NT; t += 256) s += num[t] / (den[t] + 1e-5f);
#pragma unroll
    for (int off = 32; off > 0; off >>= 1) s += __shfl_down(s, off, 64);
    __shared__ float red[4];
    if ((tid & 63) == 0) red[tid >> 6] = s;
    __syncthreads();
    if (tid == 0) out[0] = (red[0] + red[1] + red[2] + red[3]) / (float)NT;
}

extern "C" void kernel_launch(void* const* d_in, const int* in_sizes, int n_in,
                              void* d_out, int out_size, void* d_ws, size_t ws_size,
                              hipStream_t stream) {
    const float* values  = (const float*)d_in[0];
    const float* masks   = (const float*)d_in[1];
    const float* evals   = (const float*)d_in[2];
    const float* emask   = (const float*)d_in[3];
    const float* istrain = (const float*)d_in[4];
    const float* W_ih    = (const float*)d_in[5];
    const float* W_hh    = (const float*)d_in[6];
    const float* b_ih    = (const float*)d_in[7];
    const float* b_hh    = (const float*)d_in[8];
    const float* W_reg   = (const float*)d_in[9];
    const float* b_reg   = (const float*)d_in[10];

    float* out = (float*)d_out;
    float* num = (float*)d_ws;       // NT floats
    float* den = num + NT;           // NT floats

    copy_zero_kernel<<<1024, 256, 0, stream>>>(evals, emask, istrain, out, num);
    lstm_kernel<<<NB / 4, 64, 0, stream>>>(values, masks, W_ih, W_hh, b_ih, b_hh,
                                           W_reg, b_reg, out + OFF_IMP, num, den);
    loss_kernel<<<1, 256, 0, stream>>>(num, den, out);
}